// Round 1
// baseline (1021.527 us; speedup 1.0000x reference)
//
#include <hip/hip_runtime.h>
#include <math.h>

// Problem constants (B,H,S,D) = (2,16,2048,64), fp32 in, fp32 out.
constexpr int Bc = 2, Hc = 16, Sc = 2048, Dc = 64;
constexpr int BM = 64;   // q rows per block
constexpr int BN = 64;   // k rows per tile
constexpr int LDQ = 72;  // padded LDS stride (elements) for Qs/Ks/Ps: 144B rows, 16B-aligned, 2-way-free b128 reads
constexpr int LDV = 66;  // padded LDS stride for Vs: breaks the 8-way conflict on strided B-frag reads
constexpr float SCALE = 0.125f; // 1/sqrt(64)

typedef __bf16 bf16_t;
typedef __bf16 bf16x8 __attribute__((ext_vector_type(8)));
typedef __bf16 bf16x4 __attribute__((ext_vector_type(4)));
typedef __bf16 bf16x2 __attribute__((ext_vector_type(2)));
typedef float floatx4 __attribute__((ext_vector_type(4)));

#define MFMA16(a, b, c) __builtin_amdgcn_mfma_f32_16x16x32_bf16((a), (b), (c), 0, 0, 0)

__global__ __launch_bounds__(256, 2)
void sdpa_fused_kernel(const float* __restrict__ Q, const float* __restrict__ K,
                       const float* __restrict__ V, const int* __restrict__ Mask,
                       float* __restrict__ CtxOut, float* __restrict__ ProbOut)
{
    __shared__ bf16_t Qs[BM * LDQ];
    __shared__ bf16_t Ks[BN * LDQ];
    __shared__ bf16_t Vs[BN * LDV];
    __shared__ bf16_t Ps[BM * LDQ];  // wave w owns rows [16w, 16w+16)

    const int tid  = threadIdx.x;
    const int wave = tid >> 6;
    const int lane = tid & 63;
    const int quad = lane >> 4;
    const int l16  = lane & 15;

    const int qt    = blockIdx.x;       // q tile index
    const int bh    = blockIdx.y;       // b*H + h
    const int b     = bh >> 4;          // H = 16
    const int qbase = qt * BM;

    const float* Qp = Q + ((size_t)bh * Sc + qbase) * Dc;
    const float* Kp = K + (size_t)bh * Sc * Dc;
    const float* Vp = V + (size_t)bh * Sc * Dc;
    const int*   Mp = Mask + (size_t)b * Sc * Sc;
    float* Pg = ProbOut + (size_t)bh * Sc * Sc;
    float* Cg = CtxOut + ((size_t)bh * Sc + qbase) * Dc;

    // ---- stage Q tile (64x64 fp32 -> bf16 LDS) ----
    #pragma unroll
    for (int t = 0; t < 4; ++t) {
        int i = tid + t * 256;          // float4 index, 1024 total
        int r = i >> 4;                 // 16 float4 per row
        int c = (i & 15) << 2;
        float4 v = *reinterpret_cast<const float4*>(Qp + r * Dc + c);
        bf16x4 w; w[0] = (bf16_t)v.x; w[1] = (bf16_t)v.y; w[2] = (bf16_t)v.z; w[3] = (bf16_t)v.w;
        *reinterpret_cast<bf16x4*>(&Qs[r * LDQ + c]) = w;
    }
    __syncthreads();

    // Q A-fragments (hoisted; Qs is never overwritten). A[m=l16][k=quad*8+j].
    const int qrow_lds = wave * 16 + l16;
    bf16x8 qa0 = *reinterpret_cast<const bf16x8*>(&Qs[qrow_lds * LDQ + quad * 8]);
    bf16x8 qa1 = *reinterpret_cast<const bf16x8*>(&Qs[qrow_lds * LDQ + 32 + quad * 8]);

    float m_i[4], l_i[4];
    #pragma unroll
    for (int r = 0; r < 4; ++r) { m_i[r] = -3.0e38f; l_i[r] = 0.f; }

    const int mrow0 = qbase + wave * 16 + quad * 4;  // + r gives the global q row of acc reg r

    // ================= PASS 1: row max + sumexp (online) =================
    for (int kt = 0; kt < Sc / BN; ++kt) {
        __syncthreads();  // previous tile's LDS reads complete
        const float* Kt = Kp + (size_t)kt * BN * Dc;
        #pragma unroll
        for (int t = 0; t < 4; ++t) {
            int i = tid + t * 256;
            int r = i >> 4;
            int c = (i & 15) << 2;
            float4 v = *reinterpret_cast<const float4*>(Kt + r * Dc + c);
            bf16x4 w; w[0] = (bf16_t)v.x; w[1] = (bf16_t)v.y; w[2] = (bf16_t)v.z; w[3] = (bf16_t)v.w;
            *reinterpret_cast<bf16x4*>(&Ks[r * LDQ + c]) = w;
        }
        __syncthreads();

        floatx4 acc[4];
        #pragma unroll
        for (int nt = 0; nt < 4; ++nt) acc[nt] = (floatx4){0.f, 0.f, 0.f, 0.f};
        #pragma unroll
        for (int nt = 0; nt < 4; ++nt) {
            const bf16_t* kr = &Ks[(nt * 16 + l16) * LDQ + quad * 8];
            bf16x8 kb0 = *reinterpret_cast<const bf16x8*>(kr);
            bf16x8 kb1 = *reinterpret_cast<const bf16x8*>(kr + 32);
            acc[nt] = MFMA16(qa0, kb0, acc[nt]);
            acc[nt] = MFMA16(qa1, kb1, acc[nt]);
        }
        const int kcol0 = kt * BN;
        #pragma unroll
        for (int nt = 0; nt < 4; ++nt) {
            #pragma unroll
            for (int r = 0; r < 4; ++r) {
                float sv = acc[nt][r] * SCALE;
                int mv = Mp[(size_t)(mrow0 + r) * Sc + kcol0 + nt * 16 + l16];
                acc[nt][r] = mv ? sv : -1e9f;
            }
        }
        #pragma unroll
        for (int r = 0; r < 4; ++r) {
            float mx = fmaxf(fmaxf(acc[0][r], acc[1][r]), fmaxf(acc[2][r], acc[3][r]));
            #pragma unroll
            for (int off = 1; off < 16; off <<= 1) mx = fmaxf(mx, __shfl_xor(mx, off, 64));
            float mn = fmaxf(m_i[r], mx);
            float sum = __expf(acc[0][r] - mn) + __expf(acc[1][r] - mn) +
                        __expf(acc[2][r] - mn) + __expf(acc[3][r] - mn);
            #pragma unroll
            for (int off = 1; off < 16; off <<= 1) sum += __shfl_xor(sum, off, 64);
            l_i[r] = l_i[r] * __expf(m_i[r] - mn) + sum;
            m_i[r] = mn;
        }
    }

    float linv[4];
    #pragma unroll
    for (int r = 0; r < 4; ++r) linv[r] = 1.0f / l_i[r];

    floatx4 co[4];
    #pragma unroll
    for (int dt = 0; dt < 4; ++dt) co[dt] = (floatx4){0.f, 0.f, 0.f, 0.f};

    // ================= PASS 2: P = exp(s-m)/l, write P, PV MFMA =================
    for (int kt = 0; kt < Sc / BN; ++kt) {
        __syncthreads();
        const float* Kt = Kp + (size_t)kt * BN * Dc;
        const float* Vt = Vp + (size_t)kt * BN * Dc;
        #pragma unroll
        for (int t = 0; t < 4; ++t) {
            int i = tid + t * 256;
            int r = i >> 4;
            int c = (i & 15) << 2;
            float4 v = *reinterpret_cast<const float4*>(Kt + r * Dc + c);
            bf16x4 w; w[0] = (bf16_t)v.x; w[1] = (bf16_t)v.y; w[2] = (bf16_t)v.z; w[3] = (bf16_t)v.w;
            *reinterpret_cast<bf16x4*>(&Ks[r * LDQ + c]) = w;
            float4 u = *reinterpret_cast<const float4*>(Vt + r * Dc + c);
            bf16x2 x0; x0[0] = (bf16_t)u.x; x0[1] = (bf16_t)u.y;
            bf16x2 x1; x1[0] = (bf16_t)u.z; x1[1] = (bf16_t)u.w;
            *reinterpret_cast<bf16x2*>(&Vs[r * LDV + c]) = x0;
            *reinterpret_cast<bf16x2*>(&Vs[r * LDV + c + 2]) = x1;
        }
        __syncthreads();

        floatx4 acc[4];
        #pragma unroll
        for (int nt = 0; nt < 4; ++nt) acc[nt] = (floatx4){0.f, 0.f, 0.f, 0.f};
        #pragma unroll
        for (int nt = 0; nt < 4; ++nt) {
            const bf16_t* kr = &Ks[(nt * 16 + l16) * LDQ + quad * 8];
            bf16x8 kb0 = *reinterpret_cast<const bf16x8*>(kr);
            bf16x8 kb1 = *reinterpret_cast<const bf16x8*>(kr + 32);
            acc[nt] = MFMA16(qa0, kb0, acc[nt]);
            acc[nt] = MFMA16(qa1, kb1, acc[nt]);
        }
        const int kcol0 = kt * BN;
        #pragma unroll
        for (int nt = 0; nt < 4; ++nt) {
            #pragma unroll
            for (int r = 0; r < 4; ++r) {
                float sv = acc[nt][r] * SCALE;
                int mv = Mp[(size_t)(mrow0 + r) * Sc + kcol0 + nt * 16 + l16];
                sv = mv ? sv : -1e9f;
                float p = __expf(sv - m_i[r]) * linv[r];
                // global P write: 16 lanes of a quad write 64B contiguous
                Pg[(size_t)(mrow0 + r) * Sc + kcol0 + nt * 16 + l16] = p;
                // stage bf16 P for the PV A-fragment (wave-private region)
                Ps[(wave * 16 + quad * 4 + r) * LDQ + nt * 16 + l16] = (bf16_t)p;
            }
        }
        __syncthreads();  // Ps visible (cheap; also orders intra-wave ds_write->ds_read)

        #pragma unroll
        for (int ks = 0; ks < 2; ++ks) {
            bf16x8 pa = *reinterpret_cast<const bf16x8*>(
                &Ps[(wave * 16 + l16) * LDQ + ks * 32 + quad * 8]);
            #pragma unroll
            for (int dt = 0; dt < 4; ++dt) {
                bf16x8 vb;
                #pragma unroll
                for (int j = 0; j < 8; ++j)
                    vb[j] = Vs[(ks * 32 + quad * 8 + j) * LDV + dt * 16 + l16];
                co[dt] = MFMA16(pa, vb, co[dt]);
            }
        }
    }

    // ---- context write ----
    #pragma unroll
    for (int dt = 0; dt < 4; ++dt) {
        #pragma unroll
        for (int r = 0; r < 4; ++r) {
            Cg[(size_t)(wave * 16 + quad * 4 + r) * Dc + dt * 16 + l16] = co[dt][r];
        }
    }
}

extern "C" void kernel_launch(void* const* d_in, const int* in_sizes, int n_in,
                              void* d_out, int out_size, void* d_ws, size_t ws_size,
                              hipStream_t stream) {
    const float* Q    = (const float*)d_in[0];
    const float* K    = (const float*)d_in[1];
    const float* V    = (const float*)d_in[2];
    const int*   mask = (const int*)d_in[3];

    float* ctx  = (float*)d_out;                                   // [B,H,S,D]
    float* prob = (float*)d_out + (size_t)Bc * Hc * Sc * Dc;       // [B,H,S,S]

    dim3 grid(Sc / BM, Bc * Hc);
    sdpa_fused_kernel<<<grid, 256, 0, stream>>>(Q, K, V, mask, ctx, prob);
}